// Round 14
// baseline (230.643 us; speedup 1.0000x reference)
//
#include <hip/hip_runtime.h>
#include <hip/hip_bf16.h>
#include <math.h>

typedef __hip_bfloat16 bf16;
typedef __attribute__((ext_vector_type(8))) short bf16x8;
typedef __attribute__((ext_vector_type(4))) short bf16x4;
typedef __attribute__((ext_vector_type(4))) float f32x4;
typedef __attribute__((ext_vector_type(2))) unsigned int u32x2;

#define DIM 320
#define HEADS 8
#define DHEAD 40
#define CTXD 768
#define FFI 1280
#define NQ 4096
#define NCTX 77
#define BATCH 2

static __device__ __forceinline__ short f2bs(float v) {
    union { bf16 b; short s; } x; x.b = __float2bfloat16(v); return x.s;
}
static __device__ __forceinline__ float bs2f(short s) {
    return __uint_as_float(((unsigned)(unsigned short)s) << 16);
}
// pack truncated bf16(lo), bf16(hi) into one u32 = [hi16(hi) : hi16(lo)]
static __device__ __forceinline__ unsigned pkbf(float hi, float lo) {
    return __builtin_amdgcn_perm(__float_as_uint(hi), __float_as_uint(lo), 0x07060302u);
}

// -------- prep: weight transposes (bid<2280) + LN1 (bid>=2280), independent work -------
__global__ void __launch_bounds__(256) prep_kernel(
    const float* q1s, const float* k1s, const float* v1s, const float* o1s,
    const float* q2s, const float* o2s, const float* k2s, const float* v2s,
    const float* w1s, const float* w2s,
    short* q1d, short* k1d, short* v1d, short* o1d,
    short* q2d, short* o2d, short* k2d, short* v2d,
    short* w1d, short* w2d,
    const float* x, const float* ln1w, const float* ln1b, short* h)
{
    int bid = blockIdx.x;
    if (bid < 2280) {
        const float* W; short* Wt; int K, N, base;
        if (bid < 600) {
            int ws = bid / 100; base = bid % 100; K = DIM; N = DIM;
            W  = ws == 0 ? q1s : ws == 1 ? k1s : ws == 2 ? v1s : ws == 3 ? o1s : ws == 4 ? q2s : o2s;
            Wt = ws == 0 ? q1d : ws == 1 ? k1d : ws == 2 ? v1d : ws == 3 ? o1d : ws == 4 ? q2d : o2d;
        } else if (bid < 1080) {
            int i = bid - 600; int ws = i / 240; base = i % 240; K = CTXD; N = DIM;
            W = ws ? v2s : k2s; Wt = ws ? v2d : k2d;
        } else if (bid < 1880) {
            base = bid - 1080; K = DIM; N = 2 * FFI; W = w1s; Wt = w1d;
        } else {
            base = bid - 1880; K = FFI; N = DIM; W = w2s; Wt = w2d;
        }
        int ntx = N / 32;
        int n0 = (base % ntx) * 32, k0 = (base / ntx) * 32;
        __shared__ float T[32][33];
        int c = threadIdx.x & 31, r8 = threadIdx.x >> 5;
#pragma unroll
        for (int rr = 0; rr < 4; ++rr) {
            int r = r8 + rr * 8;
            T[r][c] = W[(size_t)(k0 + r) * N + n0 + c];
        }
        __syncthreads();
#pragma unroll
        for (int rr = 0; rr < 4; ++rr) {
            int r = r8 + rr * 8;
            Wt[(size_t)(n0 + r) * K + k0 + c] = f2bs(T[c][r]);
        }
    } else {
        int row = (bid - 2280) * 4 + (threadIdx.x >> 6);
        int lane = threadIdx.x & 63;
        float v[8];
        float s = 0.f, s2 = 0.f;
        if (lane < 40) {
            const float* rp = x + (size_t)row * DIM + lane * 8;
#pragma unroll
            for (int j = 0; j < 8; ++j) { v[j] = rp[j]; s += v[j]; s2 += v[j] * v[j]; }
        }
#pragma unroll
        for (int off = 32; off; off >>= 1) { s += __shfl_xor(s, off); s2 += __shfl_xor(s2, off); }
        float mean = s * (1.f / DIM);
        float var = s2 * (1.f / DIM) - mean * mean;
        float rstd = rsqrtf(var + 1e-5f);
        if (lane < 40) {
            bf16x8 ov;
#pragma unroll
            for (int j = 0; j < 8; ++j)
                ov[j] = f2bs((v[j] - mean) * rstd * ln1w[lane * 8 + j] + ln1b[lane * 8 + j]);
            *(bf16x8*)(h + (size_t)row * DIM + lane * 8) = ov;
        }
    }
}

// ---------------- LayerNorm (bf16 src) -------------------------------------------------
__global__ void __launch_bounds__(256) ln_b16(const short* __restrict__ srcp,
                          const float* __restrict__ w, const float* __restrict__ bp,
                          short* __restrict__ out)
{
    int row = blockIdx.x * 4 + (threadIdx.x >> 6);
    int lane = threadIdx.x & 63;
    float v[8];
    float s = 0.f, s2 = 0.f;
    if (lane < 40) {
        bf16x8 xv = *(const bf16x8*)(srcp + (size_t)row * DIM + lane * 8);
#pragma unroll
        for (int j = 0; j < 8; ++j) { v[j] = bs2f(xv[j]); s += v[j]; s2 += v[j] * v[j]; }
    }
#pragma unroll
    for (int off = 32; off; off >>= 1) { s += __shfl_xor(s, off); s2 += __shfl_xor(s2, off); }
    float mean = s * (1.f / DIM);
    float var = s2 * (1.f / DIM) - mean * mean;
    float rstd = rsqrtf(var + 1e-5f);
    if (lane < 40) {
        bf16x8 ov;
#pragma unroll
        for (int j = 0; j < 8; ++j)
            ov[j] = f2bs((v[j] - mean) * rstd * w[lane * 8 + j] + bp[lane * 8 + j]);
        *(bf16x8*)(out + (size_t)row * DIM + lane * 8) = ov;
    }
}

// ---------------- Combine split-attention partials: out = (O1+O2)/(l1+l2) --------------
__global__ void __launch_bounds__(256) combine_attn(const short* __restrict__ Opart,
                          const float* __restrict__ lp, short* __restrict__ out)
{
    int row = blockIdx.x * 4 + (threadIdx.x >> 6);
    int lane = threadIdx.x & 63;
    if (lane >= 40) return;
    int c = lane * 8;
    int hh = c / DHEAD;
    int b_ = row >> 12, q = row & (NQ - 1);
    float l = lp[((size_t)(0 * 2 + b_) * HEADS + hh) * NQ + q]
            + lp[((size_t)(1 * 2 + b_) * HEADS + hh) * NQ + q];
    float inv = 1.f / l;
    bf16x8 o1 = *(const bf16x8*)(Opart + (size_t)row * DIM + c);
    bf16x8 o2 = *(const bf16x8*)(Opart + (size_t)(BATCH * NQ) * DIM + (size_t)row * DIM + c);
    bf16x8 ov;
#pragma unroll
    for (int j = 0; j < 8; ++j) ov[j] = f2bs((bs2f(o1[j]) + bs2f(o2[j])) * inv);
    *(bf16x8*)(out + (size_t)row * DIM + c) = ov;
}

// ============ 128x64 GEMM core: BM=128, BN=64, BK=64, 4 waves (2x2), wave=64x32 ========
template<int MODE>
__global__ void __launch_bounds__(256) gemm128(const short* __restrict__ A,
                          const short* __restrict__ Wt,
                          const float* __restrict__ bias,
                          const float* __restrict__ res,
                          short* __restrict__ resb,
                          short* __restrict__ outb,
                          float* __restrict__ outf,
                          int N, int K, float oscale)
{
    __shared__ short As[128 * 72];
    __shared__ short Bs[64 * 72];
    const int tid = threadIdx.x;
    const int w = tid >> 6, lane = tid & 63, lrow = lane & 15, lgrp = lane >> 4;
    const int wr = w >> 1, wc = w & 1;
    const int m0 = blockIdx.y * 128, n0 = blockIdx.x * 64;
    f32x4 acc[4][2] = {};
    for (int k0 = 0; k0 < K; k0 += 64) {
        __syncthreads();
#pragma unroll
        for (int l = 0; l < 4; ++l) {
            int idx = tid + (l << 8);
            int arow = idx >> 3, ac = idx & 7;
            *(bf16x8*)&As[arow * 72 + ac * 8] =
                *(const bf16x8*)(A + (size_t)(m0 + arow) * K + k0 + ac * 8);
        }
#pragma unroll
        for (int l = 0; l < 2; ++l) {
            int idx = tid + (l << 8);
            int brow = idx >> 3, bc = idx & 7;
            *(bf16x8*)&Bs[brow * 72 + bc * 8] =
                *(const bf16x8*)(Wt + (size_t)(n0 + brow) * K + k0 + bc * 8);
        }
        __syncthreads();
#pragma unroll
        for (int s = 0; s < 2; ++s) {
            bf16x8 b0 = *(const bf16x8*)&Bs[(wc * 32 + lrow) * 72 + s * 32 + lgrp * 8];
            bf16x8 b1 = *(const bf16x8*)&Bs[(wc * 32 + 16 + lrow) * 72 + s * 32 + lgrp * 8];
#pragma unroll
            for (int m = 0; m < 4; ++m) {
                bf16x8 a = *(const bf16x8*)&As[(wr * 64 + m * 16 + lrow) * 72 + s * 32 + lgrp * 8];
                acc[m][0] = __builtin_amdgcn_mfma_f32_16x16x32_bf16(a, b0, acc[m][0], 0, 0, 0);
                acc[m][1] = __builtin_amdgcn_mfma_f32_16x16x32_bf16(a, b1, acc[m][1], 0, 0, 0);
            }
        }
    }
#pragma unroll
    for (int n = 0; n < 2; ++n) {
        int col = n0 + wc * 32 + n * 16 + lrow;
        float bvx = bias ? bias[col] : 0.f;
#pragma unroll
        for (int m = 0; m < 4; ++m) {
#pragma unroll
            for (int r = 0; r < 4; ++r) {
                int row = m0 + wr * 64 + m * 16 + lgrp * 4 + r;
                float v = acc[m][n][r] + bvx;
                size_t o = (size_t)row * N + col;
                if (MODE == 0)      outb[o] = f2bs(v * oscale);
                else if (MODE == 1) resb[o] = f2bs(v + res[o]);
                else if (MODE == 2) resb[o] = f2bs(v + bs2f(resb[o]));
                else                outf[o] = v + bs2f(resb[o]);
            }
        }
    }
}

// ---------------- QKV on the 128x64 core: z=0 Q(scaled), z=1 K, z=2 V(transposed) ------
__global__ void __launch_bounds__(256) qkv128(const short* __restrict__ A,
                          const short* __restrict__ wq, const short* __restrict__ wk,
                          const short* __restrict__ wv,
                          short* __restrict__ qb, short* __restrict__ kbuf,
                          short* __restrict__ vts, float qscale)
{
    __shared__ short As[128 * 72];
    __shared__ short Bs[64 * 72];
    const int tid = threadIdx.x;
    const int z = blockIdx.z;
    const short* Wt = z == 0 ? wq : z == 1 ? wk : wv;
    const int w = tid >> 6, lane = tid & 63, lrow = lane & 15, lgrp = lane >> 4;
    const int wr = w >> 1, wc = w & 1;
    const int m0 = blockIdx.y * 128, n0 = blockIdx.x * 64;
    f32x4 acc[4][2] = {};
    for (int k0 = 0; k0 < DIM; k0 += 64) {
        __syncthreads();
#pragma unroll
        for (int l = 0; l < 4; ++l) {
            int idx = tid + (l << 8);
            int arow = idx >> 3, ac = idx & 7;
            *(bf16x8*)&As[arow * 72 + ac * 8] =
                *(const bf16x8*)(A + (size_t)(m0 + arow) * DIM + k0 + ac * 8);
        }
#pragma unroll
        for (int l = 0; l < 2; ++l) {
            int idx = tid + (l << 8);
            int brow = idx >> 3, bc = idx & 7;
            *(bf16x8*)&Bs[brow * 72 + bc * 8] =
                *(const bf16x8*)(Wt + (size_t)(n0 + brow) * DIM + k0 + bc * 8);
        }
        __syncthreads();
#pragma unroll
        for (int s = 0; s < 2; ++s) {
            bf16x8 b0 = *(const bf16x8*)&Bs[(wc * 32 + lrow) * 72 + s * 32 + lgrp * 8];
            bf16x8 b1 = *(const bf16x8*)&Bs[(wc * 32 + 16 + lrow) * 72 + s * 32 + lgrp * 8];
#pragma unroll
            for (int m = 0; m < 4; ++m) {
                bf16x8 a = *(const bf16x8*)&As[(wr * 64 + m * 16 + lrow) * 72 + s * 32 + lgrp * 8];
                acc[m][0] = __builtin_amdgcn_mfma_f32_16x16x32_bf16(a, b0, acc[m][0], 0, 0, 0);
                acc[m][1] = __builtin_amdgcn_mfma_f32_16x16x32_bf16(a, b1, acc[m][1], 0, 0, 0);
            }
        }
    }
#pragma unroll
    for (int n = 0; n < 2; ++n) {
        int col = n0 + wc * 32 + n * 16 + lrow;
#pragma unroll
        for (int m = 0; m < 4; ++m) {
            if (z == 2) {
                int row0 = m0 + wr * 64 + m * 16 + lgrp * 4;
                int b_ = row0 >> 12, kv = row0 & (NQ - 1);
                int hh = col / DHEAD, d = col - hh * DHEAD;
                bf16x4 pv;
#pragma unroll
                for (int r = 0; r < 4; ++r) pv[r] = f2bs(acc[m][n][r]);
                *(bf16x4*)(vts + (size_t)((b_ * HEADS + hh) * 48 + d) * NQ + kv) = pv;
            } else {
#pragma unroll
                for (int r = 0; r < 4; ++r) {
                    int row = m0 + wr * 64 + m * 16 + lgrp * 4 + r;
                    float v = acc[m][n][r];
                    if (z == 0) qb[(size_t)row * DIM + col] = f2bs(v * qscale);
                    else        kbuf[(size_t)row * DIM + col] = f2bs(v);
                }
            }
        }
    }
}

// -------- Merged cross-Q (bid<320) + cross-K/V (bid>=320): independent, one launch -----
__global__ void __launch_bounds__(256) crossq_kv(const short* __restrict__ h,
                          const short* __restrict__ wq2,
                          const float* __restrict__ ctx,
                          const short* __restrict__ wk2, const short* __restrict__ wv2,
                          short* __restrict__ qb, short* __restrict__ k2,
                          short* __restrict__ vt2, float qscale)
{
    __shared__ short As[128 * 72];
    __shared__ short Bs[64 * 72];
    const int tid = threadIdx.x;
    const int w = tid >> 6, lane = tid & 63, lrow = lane & 15, lgrp = lane >> 4;
    int bid = blockIdx.x;
    if (bid < 320) {
        const int wr = w >> 1, wc = w & 1;
        const int m0 = (bid / 5) * 128, n0 = (bid % 5) * 64;
        f32x4 acc[4][2] = {};
        for (int k0 = 0; k0 < DIM; k0 += 64) {
            __syncthreads();
#pragma unroll
            for (int l = 0; l < 4; ++l) {
                int idx = tid + (l << 8);
                int arow = idx >> 3, ac = idx & 7;
                *(bf16x8*)&As[arow * 72 + ac * 8] =
                    *(const bf16x8*)(h + (size_t)(m0 + arow) * DIM + k0 + ac * 8);
            }
#pragma unroll
            for (int l = 0; l < 2; ++l) {
                int idx = tid + (l << 8);
                int brow = idx >> 3, bc = idx & 7;
                *(bf16x8*)&Bs[brow * 72 + bc * 8] =
                    *(const bf16x8*)(wq2 + (size_t)(n0 + brow) * DIM + k0 + bc * 8);
            }
            __syncthreads();
#pragma unroll
            for (int s = 0; s < 2; ++s) {
                bf16x8 b0 = *(const bf16x8*)&Bs[(wc * 32 + lrow) * 72 + s * 32 + lgrp * 8];
                bf16x8 b1 = *(const bf16x8*)&Bs[(wc * 32 + 16 + lrow) * 72 + s * 32 + lgrp * 8];
#pragma unroll
                for (int m = 0; m < 4; ++m) {
                    bf16x8 a = *(const bf16x8*)&As[(wr * 64 + m * 16 + lrow) * 72 + s * 32 + lgrp * 8];
                    acc[m][0] = __builtin_amdgcn_mfma_f32_16x16x32_bf16(a, b0, acc[m][0], 0, 0, 0);
                    acc[m][1] = __builtin_amdgcn_mfma_f32_16x16x32_bf16(a, b1, acc[m][1], 0, 0, 0);
                }
            }
        }
#pragma unroll
        for (int n = 0; n < 2; ++n) {
            int col = n0 + wc * 32 + n * 16 + lrow;
#pragma unroll
            for (int m = 0; m < 4; ++m)
#pragma unroll
                for (int r = 0; r < 4; ++r) {
                    int row = m0 + wr * 64 + m * 16 + lgrp * 4 + r;
                    qb[(size_t)row * DIM + col] = f2bs(acc[m][n][r] * qscale);
                }
        }
    } else {
        int i = bid - 320;
        int z = i / 15, r_ = i % 15;
        const short* Wt = z ? wv2 : wk2;
        const int Mc = BATCH * NCTX;
        const int m0 = (r_ / 5) * 64, n0 = (r_ % 5) * 64;
        f32x4 acc[4] = {};
        for (int kb = 0; kb < CTXD / 64; ++kb) {
            const int k0 = kb << 6;
            __syncthreads();
#pragma unroll
            for (int l = 0; l < 2; ++l) {
                int idx = tid + (l << 8);
                int arow = idx >> 3, ac = idx & 7;
                int grow = m0 + arow;
                bf16x8 v = {};
                if (grow < Mc) {
                    const float* Af = ctx + (size_t)grow * CTXD + k0 + ac * 8;
#pragma unroll
                    for (int j = 0; j < 8; ++j) v[j] = f2bs(Af[j]);
                }
                *(bf16x8*)&As[arow * 72 + ac * 8] = v;
                *(bf16x8*)&Bs[arow * 72 + ac * 8] =
                    *(const bf16x8*)(Wt + (size_t)(n0 + arow) * CTXD + k0 + ac * 8);
            }
            __syncthreads();
#pragma unroll
            for (int s = 0; s < 2; ++s) {
                bf16x8 a = *(const bf16x8*)&As[(w * 16 + lrow) * 72 + s * 32 + lgrp * 8];
#pragma unroll
                for (int ct = 0; ct < 4; ++ct) {
                    bf16x8 b = *(const bf16x8*)&Bs[(ct * 16 + lrow) * 72 + s * 32 + lgrp * 8];
                    acc[ct] = __builtin_amdgcn_mfma_f32_16x16x32_bf16(a, b, acc[ct], 0, 0, 0);
                }
            }
        }
#pragma unroll
        for (int ct = 0; ct < 4; ++ct) {
            int col = n0 + ct * 16 + lrow;
            int hh = col / DHEAD, d = col - hh * DHEAD;
#pragma unroll
            for (int r = 0; r < 4; ++r) {
                int row = m0 + w * 16 + lgrp * 4 + r;
                if (row >= Mc) continue;
                float v = acc[ct][r];
                if (z == 0) k2[(size_t)row * DIM + col] = f2bs(v);
                else {
                    int b_ = row / NCTX, kv = row - b_ * NCTX;
                    vt2[(size_t)((b_ * HEADS + hh) * 48 + d) * 128 + kv] = f2bs(v);
                }
            }
        }
    }
}

// ---------------- GEGLU on the 128x64 core: dual B tiles (u + gate) --------------------
__global__ void __launch_bounds__(256) geglu128(const short* __restrict__ A,
                           const short* __restrict__ Wt1,
                           const float* __restrict__ b1, short* __restrict__ G)
{
    __shared__ short As[128 * 72];
    __shared__ short Bu[64 * 72];
    __shared__ short Bg[64 * 72];
    const int tid = threadIdx.x;
    const int w = tid >> 6, lane = tid & 63, lrow = lane & 15, lgrp = lane >> 4;
    const int wr = w >> 1, wc = w & 1;
    const int m0 = blockIdx.y * 128, n0 = blockIdx.x * 64;
    f32x4 au[4][2] = {}, ag[4][2] = {};
    for (int k0 = 0; k0 < DIM; k0 += 64) {
        __syncthreads();
#pragma unroll
        for (int l = 0; l < 4; ++l) {
            int idx = tid + (l << 8);
            int arow = idx >> 3, ac = idx & 7;
            *(bf16x8*)&As[arow * 72 + ac * 8] =
                *(const bf16x8*)(A + (size_t)(m0 + arow) * DIM + k0 + ac * 8);
        }
#pragma unroll
        for (int l = 0; l < 2; ++l) {
            int idx = tid + (l << 8);
            int brow = idx >> 3, bc = idx & 7;
            *(bf16x8*)&Bu[brow * 72 + bc * 8] =
                *(const bf16x8*)(Wt1 + (size_t)(n0 + brow) * DIM + k0 + bc * 8);
            *(bf16x8*)&Bg[brow * 72 + bc * 8] =
                *(const bf16x8*)(Wt1 + (size_t)(FFI + n0 + brow) * DIM + k0 + bc * 8);
        }
        __syncthreads();
#pragma unroll
        for (int s = 0; s < 2; ++s) {
            bf16x8 bu0 = *(const bf16x8*)&Bu[(wc * 32 + lrow) * 72 + s * 32 + lgrp * 8];
            bf16x8 bu1 = *(const bf16x8*)&Bu[(wc * 32 + 16 + lrow) * 72 + s * 32 + lgrp * 8];
            bf16x8 bg0 = *(const bf16x8*)&Bg[(wc * 32 + lrow) * 72 + s * 32 + lgrp * 8];
            bf16x8 bg1 = *(const bf16x8*)&Bg[(wc * 32 + 16 + lrow) * 72 + s * 32 + lgrp * 8];
#pragma unroll
            for (int m = 0; m < 4; ++m) {
                bf16x8 a = *(const bf16x8*)&As[(wr * 64 + m * 16 + lrow) * 72 + s * 32 + lgrp * 8];
                au[m][0] = __builtin_amdgcn_mfma_f32_16x16x32_bf16(a, bu0, au[m][0], 0, 0, 0);
                au[m][1] = __builtin_amdgcn_mfma_f32_16x16x32_bf16(a, bu1, au[m][1], 0, 0, 0);
                ag[m][0] = __builtin_amdgcn_mfma_f32_16x16x32_bf16(a, bg0, ag[m][0], 0, 0, 0);
                ag[m][1] = __builtin_amdgcn_mfma_f32_16x16x32_bf16(a, bg1, ag[m][1], 0, 0, 0);
            }
        }
    }
#pragma unroll
    for (int n = 0; n < 2; ++n) {
        int col = n0 + wc * 32 + n * 16 + lrow;
        float bu = b1[col], bg = b1[FFI + col];
#pragma unroll
        for (int m = 0; m < 4; ++m) {
#pragma unroll
            for (int r = 0; r < 4; ++r) {
                int row = m0 + wr * 64 + m * 16 + lgrp * 4 + r;
                float u = au[m][n][r] + bu;
                float g = ag[m][n][r] + bg;
                float gelu = 0.5f * g * (1.f + erff(g * 0.70710678f));
                G[(size_t)row * FFI + col] = f2bs(u * gelu);
            }
        }
    }
}

// ---------------- Flash attention core loop (shared by split-self and cross) -----------
// Dual-q waves, deferred PV, single P buffer, K dbuf + V tbuf LDS pipeline.
// SELF-SPLIT: grid z = (b,half); each block does kv in [half*2048, half*2048+2048),
//   writes UNNORMALIZED bf16 O-partial + per-(q,h) l to lp. Combine kernel finishes.
// CROSS (SPLIT=false): kvlen=77 masked, normalized write to O.
template<bool SPLIT>
__global__ void __launch_bounds__(256) flash_mfma(const short* __restrict__ Q,
                           const short* __restrict__ Kb,
                           const short* __restrict__ VtG,
                           short* __restrict__ O,
                           float* __restrict__ lp,
                           int kvlen, int kvs, int ntiles)
{
    __shared__ short Ks[2][64 * 64];
    __shared__ short Vt[3][48 * 64];
    __shared__ short Ps[128 * 64];
    const int tid = threadIdx.x;
    const int w = tid >> 6, lane = tid & 63, lrow = lane & 15, lgrp = lane >> 4;
    const int hh = blockIdx.y;
    const int zb = blockIdx.z;
    const int b = SPLIT ? (zb >> 1) : zb;
    const int hf = SPLIT ? (zb & 1) : 0;
    const int kvoff = hf * 2048;
    const int q0 = blockIdx.x * 128;
    const int swz = (lrow & 7) << 4;

    for (int i = tid; i < 1024; i += 256) ((bf16x8*)Ks)[i] = (bf16x8){};
    for (int i = tid; i < 1152; i += 256) {
        short fill = (((i % 384) >> 3) == 40) ? (short)0x3F80 : (short)0;  // ones row d=40
        bf16x8 f8 = {fill, fill, fill, fill, fill, fill, fill, fill};
        ((bf16x8*)Vt)[i] = f8;
    }

    const size_t qra = (size_t)(b * NQ + q0 + w * 32 + lrow) * DIM + hh * DHEAD;
    const size_t qrb = qra + (size_t)16 * DIM;
    bf16x8 bq0a = *(const bf16x8*)(Q + qra + lgrp * 8);
    bf16x8 bq0b = *(const bf16x8*)(Q + qrb + lgrp * 8);
    bf16x8 bq1a = {}, bq1b = {};
    if (lgrp == 0) {
        bq1a = *(const bf16x8*)(Q + qra + 32);
        bq1b = *(const bf16x8*)(Q + qrb + 32);
    }

    const int kv0 = tid / 5, cc0 = tid % 5;
    const bool isK1 = tid < 64;
    const int kv1 = (256 + tid) / 5, cc1 = (256 + tid) % 5;
    const int vd1 = (tid - 64) >> 3, vcc1 = (tid - 64) & 7;
    const bool hasV2 = tid < 128;
    const int vd2 = (192 + tid) >> 3, vcc2 = (192 + tid) & 7;

    const size_t kbase = (size_t)b * kvlen + kvoff;
    const size_t vbase = (size_t)((b * HEADS + hh) * 48);

    const short* kp0 = Kb + (kbase + kv0) * DIM + hh * DHEAD + cc0 * 8;
    const short* kp1 = Kb + (kbase + (isK1 ? kv1 : 0)) * DIM + hh * DHEAD + (isK1 ? cc1 : 0) * 8;
    const short* vp1 = VtG + (vbase + (isK1 ? 0 : vd1)) * kvs + kvoff + (isK1 ? 0 : vcc1) * 8;
    const short* vp2 = VtG + (vbase + (hasV2 ? vd2 : 0)) * kvs + kvoff + (hasV2 ? vcc2 : 0) * 8;

    const int koff0 = kv0 * 128 + ((cc0 * 16) ^ ((kv0 & 7) << 4));
    const int koff1 = kv1 * 128 + ((cc1 * 16) ^ ((kv1 & 7) << 4));
    const int voff1 = vd1 * 128 + ((vcc1 * 16) ^ ((vd1 & 7) << 4));
    const int voff2 = vd2 * 128 + ((vcc2 * 16) ^ ((vd2 & 7) << 4));

    bf16x8 st0, st1, st2;
    auto issue = [&]() {
        st0 = *(const bf16x8*)kp0; kp0 += 64 * DIM;
        if (isK1) { st1 = *(const bf16x8*)kp1; kp1 += 64 * DIM; }
        else      { st1 = *(const bf16x8*)vp1; vp1 += 64; }
        if (hasV2) { st2 = *(const bf16x8*)vp2; vp2 += 64; }
    };
    auto commit = [&](char* kb_, char* vb_) {
        *(bf16x8*)(kb_ + koff0) = st0;
        if (isK1)  *(bf16x8*)(kb_ + koff1) = st1;
        else       *(bf16x8*)(vb_ + voff1) = st1;
        if (hasV2) *(bf16x8*)(vb_ + voff2) = st2;
    };

    f32x4 oa[3] = {}, ob[3] = {};

    char* kcur = (char*)Ks[0];
    char* knxt = (char*)Ks[1];
    char* vprev = (char*)Vt[2];
    char* vcur  = (char*)Vt[0];
    char* vnxt  = (char*)Vt[1];
    char* pp = (char*)Ps + (w * 32 + lrow) * 128;

    auto pv_step = [&](char* vb_) {
        __builtin_amdgcn_s_setprio(1);
#pragma unroll
        for (int s = 0; s < 2; ++s) {
            bf16x8 bpa = *(const bf16x8*)(pp + ((s * 64 + lgrp * 16) ^ swz));
            bf16x8 bpb = *(const bf16x8*)(pp + 2048 + ((s * 64 + lgrp * 16) ^ swz));
#pragma unroll
            for (int dt = 0; dt < 3; ++dt) {
                bf16x8 av = *(const bf16x8*)(vb_ + (dt * 16 + lrow) * 128 + ((s * 64 + lgrp * 16) ^ swz));
                oa[dt] = __builtin_amdgcn_mfma_f32_16x16x32_bf16(av, bpa, oa[dt], 0, 0, 0);
                ob[dt] = __builtin_amdgcn_mfma_f32_16x16x32_bf16(av, bpb, ob[dt], 0, 0, 0);
            }
        }
        __builtin_amdgcn_s_setprio(0);
    };

    issue();
    __syncthreads();
    commit(kcur, vcur);
    issue();

    for (int t = 0; t < ntiles; ++t) {
        __syncthreads();
        commit(knxt, vnxt);
        issue();

        if (t > 0) pv_step(vprev);

        f32x4 sa[4] = {}, sb[4] = {};
        __builtin_amdgcn_s_setprio(1);
#pragma unroll
        for (int ct = 0; ct < 4; ++ct) {
            const char* krow = kcur + (ct * 16 + lrow) * 128;
            bf16x8 ak0 = *(const bf16x8*)(krow + ((lgrp * 16) ^ swz));
            bf16x8 ak1 = *(const bf16x8*)(krow + ((64 + lgrp * 16) ^ swz));
            sa[ct] = __builtin_amdgcn_mfma_f32_16x16x32_bf16(ak0, bq0a, sa[ct], 0, 0, 0);
            sb[ct] = __builtin_amdgcn_mfma_f32_16x16x32_bf16(ak0, bq0b, sb[ct], 0, 0, 0);
            sa[ct] = __builtin_amdgcn_mfma_f32_16x16x32_bf16(ak1, bq1a, sa[ct], 0, 0, 0);
            sb[ct] = __builtin_amdgcn_mfma_f32_16x16x32_bf16(ak1, bq1b, sb[ct], 0, 0, 0);
        }
        __builtin_amdgcn_s_setprio(0);
        if (!SPLIT && (t << 6) + 64 > kvlen) {
#pragma unroll
            for (int ct = 0; ct < 4; ++ct)
#pragma unroll
                for (int r = 0; r < 4; ++r)
                    if ((t << 6) + ct * 16 + lgrp * 4 + r >= kvlen) { sa[ct][r] = -1e30f; sb[ct][r] = -1e30f; }
        }
#pragma unroll
        for (int ct = 0; ct < 4; ++ct) {
            float a0 = __builtin_amdgcn_exp2f(sa[ct][0]);
            float a1 = __builtin_amdgcn_exp2f(sa[ct][1]);
            float a2 = __builtin_amdgcn_exp2f(sa[ct][2]);
            float a3 = __builtin_amdgcn_exp2f(sa[ct][3]);
            u32x2 pka; pka[0] = pkbf(a1, a0); pka[1] = pkbf(a3, a2);
            *(u32x2*)(pp + ((ct * 32 + lgrp * 8) ^ swz)) = pka;
            float b0 = __builtin_amdgcn_exp2f(sb[ct][0]);
            float b1 = __builtin_amdgcn_exp2f(sb[ct][1]);
            float b2 = __builtin_amdgcn_exp2f(sb[ct][2]);
            float b3 = __builtin_amdgcn_exp2f(sb[ct][3]);
            u32x2 pkb; pkb[0] = pkbf(b1, b0); pkb[1] = pkbf(b3, b2);
            *(u32x2*)(pp + 2048 + ((ct * 32 + lgrp * 8) ^ swz)) = pkb;
        }
        { char* tk = kcur; kcur = knxt; knxt = tk; }
        { char* tv = vprev; vprev = vcur; vcur = vnxt; vnxt = tv; }
    }
    pv_step(vprev);

    if (SPLIT) {
        // l per (hf,b,h,q): lanes with lgrp==2 hold l in o*[2][0] for q = lrow (+16 for group b)
        if (lgrp == 2) {
            size_t lb = ((size_t)(hf * BATCH + b) * HEADS + hh) * NQ + q0 + w * 32;
            lp[lb + lrow] = oa[2][0];
            lp[lb + 16 + lrow] = ob[2][0];
        }
        const size_t obase = (size_t)hf * BATCH * NQ * DIM;
#pragma unroll
        for (int dt = 0; dt < 3; ++dt) {
            int dbase = dt * 16 + lgrp * 4;
            if (dbase < DHEAD) {
                u32x2 ova, ovb;
                ova[0] = pkbf(oa[dt][1], oa[dt][0]);
                ova[1] = pkbf(oa[dt][3], oa[dt][2]);
                *(u32x2*)(O + obase + qra + dbase) = ova;
                ovb[0] = pkbf(ob[dt][1], ob[dt][0]);
                ovb[1] = pkbf(ob[dt][3], ob[dt][2]);
                *(u32x2*)(O + obase + qrb + dbase) = ovb;
            }
        }
    } else {
        float la = __shfl(oa[2][0], 32 + lrow);
        float lb2 = __shfl(ob[2][0], 32 + lrow);
        float ia = 1.f / la, ib = 1.f / lb2;
#pragma unroll
        for (int dt = 0; dt < 3; ++dt) {
            int dbase = dt * 16 + lgrp * 4;
            if (dbase < DHEAD) {
                u32x2 ova, ovb;
                ova[0] = pkbf(oa[dt][1] * ia, oa[dt][0] * ia);
                ova[1] = pkbf(oa[dt][3] * ia, oa[dt][2] * ia);
                *(u32x2*)(O + qra + dbase) = ova;
                ovb[0] = pkbf(ob[dt][1] * ib, ob[dt][0] * ib);
                ovb[1] = pkbf(ob[dt][3] * ib, ob[dt][2] * ib);
                *(u32x2*)(O + qrb + dbase) = ovb;
            }
        }
    }
}

extern "C" void kernel_launch(void* const* d_in, const int* in_sizes, int n_in,
                              void* d_out, int out_size, void* d_ws, size_t ws_size,
                              hipStream_t stream)
{
    const float* x      = (const float*)d_in[0];
    const float* ctx    = (const float*)d_in[1];
    const float* ln1_w  = (const float*)d_in[2];
    const float* ln1_b  = (const float*)d_in[3];
    const float* ln2_w  = (const float*)d_in[4];
    const float* ln2_b  = (const float*)d_in[5];
    const float* ln3_w  = (const float*)d_in[6];
    const float* ln3_b  = (const float*)d_in[7];
    const float* a1_Wq  = (const float*)d_in[8];
    const float* a1_Wk  = (const float*)d_in[9];
    const float* a1_Wv  = (const float*)d_in[10];
    const float* a1_Wo  = (const float*)d_in[11];
    const float* a1_bo  = (const float*)d_in[12];
    const float* a2_Wq  = (const float*)d_in[13];
    const float* a2_Wk  = (const float*)d_in[14];
    const float* a2_Wv  = (const float*)d_in[15];
    const float* a2_Wo  = (const float*)d_in[16];
    const float* a2_bo  = (const float*)d_in[17];
    const float* ff_W1  = (const float*)d_in[18];
    const float* ff_b1  = (const float*)d_in[19];
    const float* ff_W2  = (const float*)d_in[20];
    const float* ff_b2  = (const float*)d_in[21];

    const int M = BATCH * NQ;  // 8192
    const float qscale2 = (float)(0.15811388300841898 * 1.4426950408889634);

    char* p = (char*)d_ws;
    auto carve = [&](size_t bytes) { char* r = p; p += (bytes + 255) & ~255ULL; return r; };
    short* h       = (short*)carve((size_t)M * DIM * 2);
    short* qb      = (short*)carve((size_t)M * DIM * 2);
    short* kbuf    = (short*)carve((size_t)M * DIM * 2);
    short* attnout = (short*)carve((size_t)M * DIM * 2);
    short* resb    = (short*)carve((size_t)M * DIM * 2);
    short* gbuf    = (short*)carve((size_t)M * FFI * 2);
    short* VtS     = (short*)carve((size_t)BATCH * HEADS * 48 * NQ * 2);
    short* Vt2     = (short*)carve((size_t)BATCH * HEADS * 48 * 128 * 2);
    short* k2      = (short*)carve((size_t)512 * DIM * 2);
    short* Opart   = (short*)carve((size_t)2 * M * DIM * 2);
    float* lp      = (float*)carve((size_t)2 * BATCH * HEADS * NQ * 4);
    short* wtq1    = (short*)carve((size_t)DIM * DIM * 2);
    short* wtk1    = (short*)carve((size_t)DIM * DIM * 2);
    short* wtv1    = (short*)carve((size_t)DIM * DIM * 2);
    short* wto1    = (short*)carve((size_t)DIM * DIM * 2);
    short* wtq2    = (short*)carve((size_t)DIM * DIM * 2);
    short* wto2    = (short*)carve((size_t)DIM * DIM * 2);
    short* wtk2    = (short*)carve((size_t)DIM * CTXD * 2);
    short* wtv2    = (short*)carve((size_t)DIM * CTXD * 2);
    short* wt1     = (short*)carve((size_t)2 * FFI * DIM * 2);
    short* wt2     = (short*)carve((size_t)DIM * FFI * 2);

    dim3 blk(256);
    dim3 g128(DIM / 64, M / 128);            // (5,64)
    dim3 gattn_s(NQ / 128, HEADS, BATCH * 2); // (32,8,4) kv-split
    dim3 gattn_c(NQ / 128, HEADS, BATCH);     // (32,8,2) cross

    // 1. prep: all weight transposes + LN1
    prep_kernel<<<2280 + M / 4, blk, 0, stream>>>(
        a1_Wq, a1_Wk, a1_Wv, a1_Wo, a2_Wq, a2_Wo, a2_Wk, a2_Wv, ff_W1, ff_W2,
        wtq1, wtk1, wtv1, wto1, wtq2, wto2, wtk2, wtv2, wt1, wt2,
        x, ln1_w, ln1_b, h);
    // 2. self QKV
    qkv128<<<dim3(5, 64, 3), blk, 0, stream>>>(h, wtq1, wtk1, wtv1, qb, kbuf, VtS, qscale2);
    // 3. flash self-attn, kv-split x2 (unnormalized partials)
    flash_mfma<true><<<gattn_s, blk, 0, stream>>>(qb, kbuf, VtS, Opart, lp, NQ, NQ, 32);
    // 3b. combine partials -> attnout
    combine_attn<<<M / 4, blk, 0, stream>>>(Opart, lp, attnout);
    // 4. out-proj + residual
    gemm128<1><<<g128, blk, 0, stream>>>(attnout, wto1, a1_bo, x, resb, nullptr, nullptr, DIM, DIM, 1.f);
    // 5. LN2
    ln_b16<<<M / 4, blk, 0, stream>>>(resb, ln2_w, ln2_b, h);
    // 6. cross Q + cross K/V merged
    crossq_kv<<<350, blk, 0, stream>>>(h, wtq2, ctx, wtk2, wtv2, qb, k2, Vt2, qscale2);
    // 7. flash cross-attn (normalized, masked)
    flash_mfma<false><<<gattn_c, blk, 0, stream>>>(qb, k2, Vt2, attnout, nullptr, NCTX, 128, 2);
    // 8. out-proj accumulate
    gemm128<2><<<g128, blk, 0, stream>>>(attnout, wto2, a2_bo, nullptr, resb, nullptr, nullptr, DIM, DIM, 1.f);
    // 9. LN3
    ln_b16<<<M / 4, blk, 0, stream>>>(resb, ln3_w, ln3_b, h);
    // 10. GEGLU
    geglu128<<<dim3(FFI / 64, M / 128), blk, 0, stream>>>(h, wt1, ff_b1, gbuf);
    // 11. FF out + residual -> d_out (f32)
    gemm128<3><<<g128, blk, 0, stream>>>(gbuf, wt2, ff_b2, nullptr, resb, nullptr, (float*)d_out, DIM, FFI, 1.f);
}

// Round 15
// 220.966 us; speedup vs baseline: 1.0438x; 1.0438x over previous
//
#include <hip/hip_runtime.h>
#include <hip/hip_bf16.h>
#include <math.h>

typedef __hip_bfloat16 bf16;
typedef __attribute__((ext_vector_type(8))) short bf16x8;
typedef __attribute__((ext_vector_type(4))) short bf16x4;
typedef __attribute__((ext_vector_type(4))) float f32x4;
typedef __attribute__((ext_vector_type(2))) unsigned int u32x2;

#define DIM 320
#define HEADS 8
#define DHEAD 40
#define CTXD 768
#define FFI 1280
#define NQ 4096
#define NCTX 77
#define BATCH 2

static __device__ __forceinline__ short f2bs(float v) {
    union { bf16 b; short s; } x; x.b = __float2bfloat16(v); return x.s;
}
static __device__ __forceinline__ float bs2f(short s) {
    return __uint_as_float(((unsigned)(unsigned short)s) << 16);
}
// pack truncated bf16(lo), bf16(hi) into one u32 = [hi16(hi) : hi16(lo)]
static __device__ __forceinline__ unsigned pkbf(float hi, float lo) {
    return __builtin_amdgcn_perm(__float_as_uint(hi), __float_as_uint(lo), 0x07060302u);
}

// -------- prep: weight transposes (bid<2280) + LN1 (bid>=2280), independent work -------
__global__ void __launch_bounds__(256) prep_kernel(
    const float* q1s, const float* k1s, const float* v1s, const float* o1s,
    const float* q2s, const float* o2s, const float* k2s, const float* v2s,
    const float* w1s, const float* w2s,
    short* q1d, short* k1d, short* v1d, short* o1d,
    short* q2d, short* o2d, short* k2d, short* v2d,
    short* w1d, short* w2d,
    const float* x, const float* ln1w, const float* ln1b, short* h)
{
    int bid = blockIdx.x;
    if (bid < 2280) {
        const float* W; short* Wt; int K, N, base;
        if (bid < 600) {
            int ws = bid / 100; base = bid % 100; K = DIM; N = DIM;
            W  = ws == 0 ? q1s : ws == 1 ? k1s : ws == 2 ? v1s : ws == 3 ? o1s : ws == 4 ? q2s : o2s;
            Wt = ws == 0 ? q1d : ws == 1 ? k1d : ws == 2 ? v1d : ws == 3 ? o1d : ws == 4 ? q2d : o2d;
        } else if (bid < 1080) {
            int i = bid - 600; int ws = i / 240; base = i % 240; K = CTXD; N = DIM;
            W = ws ? v2s : k2s; Wt = ws ? v2d : k2d;
        } else if (bid < 1880) {
            base = bid - 1080; K = DIM; N = 2 * FFI; W = w1s; Wt = w1d;
        } else {
            base = bid - 1880; K = FFI; N = DIM; W = w2s; Wt = w2d;
        }
        int ntx = N / 32;
        int n0 = (base % ntx) * 32, k0 = (base / ntx) * 32;
        __shared__ float T[32][33];
        int c = threadIdx.x & 31, r8 = threadIdx.x >> 5;
#pragma unroll
        for (int rr = 0; rr < 4; ++rr) {
            int r = r8 + rr * 8;
            T[r][c] = W[(size_t)(k0 + r) * N + n0 + c];
        }
        __syncthreads();
#pragma unroll
        for (int rr = 0; rr < 4; ++rr) {
            int r = r8 + rr * 8;
            Wt[(size_t)(n0 + r) * K + k0 + c] = f2bs(T[c][r]);
        }
    } else {
        int row = (bid - 2280) * 4 + (threadIdx.x >> 6);
        int lane = threadIdx.x & 63;
        float v[8];
        float s = 0.f, s2 = 0.f;
        if (lane < 40) {
            const float* rp = x + (size_t)row * DIM + lane * 8;
#pragma unroll
            for (int j = 0; j < 8; ++j) { v[j] = rp[j]; s += v[j]; s2 += v[j] * v[j]; }
        }
#pragma unroll
        for (int off = 32; off; off >>= 1) { s += __shfl_xor(s, off); s2 += __shfl_xor(s2, off); }
        float mean = s * (1.f / DIM);
        float var = s2 * (1.f / DIM) - mean * mean;
        float rstd = rsqrtf(var + 1e-5f);
        if (lane < 40) {
            bf16x8 ov;
#pragma unroll
            for (int j = 0; j < 8; ++j)
                ov[j] = f2bs((v[j] - mean) * rstd * ln1w[lane * 8 + j] + ln1b[lane * 8 + j]);
            *(bf16x8*)(h + (size_t)row * DIM + lane * 8) = ov;
        }
    }
}

// ---------------- LayerNorm (bf16 src) -------------------------------------------------
__global__ void __launch_bounds__(256) ln_b16(const short* __restrict__ srcp,
                          const float* __restrict__ w, const float* __restrict__ bp,
                          short* __restrict__ out)
{
    int row = blockIdx.x * 4 + (threadIdx.x >> 6);
    int lane = threadIdx.x & 63;
    float v[8];
    float s = 0.f, s2 = 0.f;
    if (lane < 40) {
        bf16x8 xv = *(const bf16x8*)(srcp + (size_t)row * DIM + lane * 8);
#pragma unroll
        for (int j = 0; j < 8; ++j) { v[j] = bs2f(xv[j]); s += v[j]; s2 += v[j] * v[j]; }
    }
#pragma unroll
    for (int off = 32; off; off >>= 1) { s += __shfl_xor(s, off); s2 += __shfl_xor(s2, off); }
    float mean = s * (1.f / DIM);
    float var = s2 * (1.f / DIM) - mean * mean;
    float rstd = rsqrtf(var + 1e-5f);
    if (lane < 40) {
        bf16x8 ov;
#pragma unroll
        for (int j = 0; j < 8; ++j)
            ov[j] = f2bs((v[j] - mean) * rstd * w[lane * 8 + j] + bp[lane * 8 + j]);
        *(bf16x8*)(out + (size_t)row * DIM + lane * 8) = ov;
    }
}

// ============ 128x64 GEMM core: BM=128, BN=64, BK=64, 4 waves (2x2), wave=64x32 ========
template<int MODE>
__global__ void __launch_bounds__(256) gemm128(const short* __restrict__ A,
                          const short* __restrict__ Wt,
                          const float* __restrict__ bias,
                          const float* __restrict__ res,
                          short* __restrict__ resb,
                          short* __restrict__ outb,
                          float* __restrict__ outf,
                          int N, int K, float oscale)
{
    __shared__ short As[128 * 72];
    __shared__ short Bs[64 * 72];
    const int tid = threadIdx.x;
    const int w = tid >> 6, lane = tid & 63, lrow = lane & 15, lgrp = lane >> 4;
    const int wr = w >> 1, wc = w & 1;
    const int m0 = blockIdx.y * 128, n0 = blockIdx.x * 64;
    f32x4 acc[4][2] = {};
    for (int k0 = 0; k0 < K; k0 += 64) {
        __syncthreads();
#pragma unroll
        for (int l = 0; l < 4; ++l) {
            int idx = tid + (l << 8);
            int arow = idx >> 3, ac = idx & 7;
            *(bf16x8*)&As[arow * 72 + ac * 8] =
                *(const bf16x8*)(A + (size_t)(m0 + arow) * K + k0 + ac * 8);
        }
#pragma unroll
        for (int l = 0; l < 2; ++l) {
            int idx = tid + (l << 8);
            int brow = idx >> 3, bc = idx & 7;
            *(bf16x8*)&Bs[brow * 72 + bc * 8] =
                *(const bf16x8*)(Wt + (size_t)(n0 + brow) * K + k0 + bc * 8);
        }
        __syncthreads();
#pragma unroll
        for (int s = 0; s < 2; ++s) {
            bf16x8 b0 = *(const bf16x8*)&Bs[(wc * 32 + lrow) * 72 + s * 32 + lgrp * 8];
            bf16x8 b1 = *(const bf16x8*)&Bs[(wc * 32 + 16 + lrow) * 72 + s * 32 + lgrp * 8];
#pragma unroll
            for (int m = 0; m < 4; ++m) {
                bf16x8 a = *(const bf16x8*)&As[(wr * 64 + m * 16 + lrow) * 72 + s * 32 + lgrp * 8];
                acc[m][0] = __builtin_amdgcn_mfma_f32_16x16x32_bf16(a, b0, acc[m][0], 0, 0, 0);
                acc[m][1] = __builtin_amdgcn_mfma_f32_16x16x32_bf16(a, b1, acc[m][1], 0, 0, 0);
            }
        }
    }
#pragma unroll
    for (int n = 0; n < 2; ++n) {
        int col = n0 + wc * 32 + n * 16 + lrow;
        float bvx = bias ? bias[col] : 0.f;
#pragma unroll
        for (int m = 0; m < 4; ++m) {
#pragma unroll
            for (int r = 0; r < 4; ++r) {
                int row = m0 + wr * 64 + m * 16 + lgrp * 4 + r;
                float v = acc[m][n][r] + bvx;
                size_t o = (size_t)row * N + col;
                if (MODE == 0)      outb[o] = f2bs(v * oscale);
                else if (MODE == 1) resb[o] = f2bs(v + res[o]);
                else if (MODE == 2) resb[o] = f2bs(v + bs2f(resb[o]));
                else                outf[o] = v + bs2f(resb[o]);
            }
        }
    }
}

// ---------------- QKV on the 128x64 core: z=0 Q(scaled), z=1 K, z=2 V(transposed) ------
__global__ void __launch_bounds__(256) qkv128(const short* __restrict__ A,
                          const short* __restrict__ wq, const short* __restrict__ wk,
                          const short* __restrict__ wv,
                          short* __restrict__ qb, short* __restrict__ kbuf,
                          short* __restrict__ vts, float qscale)
{
    __shared__ short As[128 * 72];
    __shared__ short Bs[64 * 72];
    const int tid = threadIdx.x;
    const int z = blockIdx.z;
    const short* Wt = z == 0 ? wq : z == 1 ? wk : wv;
    const int w = tid >> 6, lane = tid & 63, lrow = lane & 15, lgrp = lane >> 4;
    const int wr = w >> 1, wc = w & 1;
    const int m0 = blockIdx.y * 128, n0 = blockIdx.x * 64;
    f32x4 acc[4][2] = {};
    for (int k0 = 0; k0 < DIM; k0 += 64) {
        __syncthreads();
#pragma unroll
        for (int l = 0; l < 4; ++l) {
            int idx = tid + (l << 8);
            int arow = idx >> 3, ac = idx & 7;
            *(bf16x8*)&As[arow * 72 + ac * 8] =
                *(const bf16x8*)(A + (size_t)(m0 + arow) * DIM + k0 + ac * 8);
        }
#pragma unroll
        for (int l = 0; l < 2; ++l) {
            int idx = tid + (l << 8);
            int brow = idx >> 3, bc = idx & 7;
            *(bf16x8*)&Bs[brow * 72 + bc * 8] =
                *(const bf16x8*)(Wt + (size_t)(n0 + brow) * DIM + k0 + bc * 8);
        }
        __syncthreads();
#pragma unroll
        for (int s = 0; s < 2; ++s) {
            bf16x8 b0 = *(const bf16x8*)&Bs[(wc * 32 + lrow) * 72 + s * 32 + lgrp * 8];
            bf16x8 b1 = *(const bf16x8*)&Bs[(wc * 32 + 16 + lrow) * 72 + s * 32 + lgrp * 8];
#pragma unroll
            for (int m = 0; m < 4; ++m) {
                bf16x8 a = *(const bf16x8*)&As[(wr * 64 + m * 16 + lrow) * 72 + s * 32 + lgrp * 8];
                acc[m][0] = __builtin_amdgcn_mfma_f32_16x16x32_bf16(a, b0, acc[m][0], 0, 0, 0);
                acc[m][1] = __builtin_amdgcn_mfma_f32_16x16x32_bf16(a, b1, acc[m][1], 0, 0, 0);
            }
        }
    }
#pragma unroll
    for (int n = 0; n < 2; ++n) {
        int col = n0 + wc * 32 + n * 16 + lrow;
#pragma unroll
        for (int m = 0; m < 4; ++m) {
            if (z == 2) {
                int row0 = m0 + wr * 64 + m * 16 + lgrp * 4;
                int b_ = row0 >> 12, kv = row0 & (NQ - 1);
                int hh = col / DHEAD, d = col - hh * DHEAD;
                bf16x4 pv;
#pragma unroll
                for (int r = 0; r < 4; ++r) pv[r] = f2bs(acc[m][n][r]);
                *(bf16x4*)(vts + (size_t)((b_ * HEADS + hh) * 48 + d) * NQ + kv) = pv;
            } else {
#pragma unroll
                for (int r = 0; r < 4; ++r) {
                    int row = m0 + wr * 64 + m * 16 + lgrp * 4 + r;
                    float v = acc[m][n][r];
                    if (z == 0) qb[(size_t)row * DIM + col] = f2bs(v * qscale);
                    else        kbuf[(size_t)row * DIM + col] = f2bs(v);
                }
            }
        }
    }
}

// -------- Merged cross-Q (bid<320) + cross-K/V (bid>=320): independent, one launch -----
__global__ void __launch_bounds__(256) crossq_kv(const short* __restrict__ h,
                          const short* __restrict__ wq2,
                          const float* __restrict__ ctx,
                          const short* __restrict__ wk2, const short* __restrict__ wv2,
                          short* __restrict__ qb, short* __restrict__ k2,
                          short* __restrict__ vt2, float qscale)
{
    __shared__ short As[128 * 72];
    __shared__ short Bs[64 * 72];
    const int tid = threadIdx.x;
    const int w = tid >> 6, lane = tid & 63, lrow = lane & 15, lgrp = lane >> 4;
    int bid = blockIdx.x;
    if (bid < 320) {
        const int wr = w >> 1, wc = w & 1;
        const int m0 = (bid / 5) * 128, n0 = (bid % 5) * 64;
        f32x4 acc[4][2] = {};
        for (int k0 = 0; k0 < DIM; k0 += 64) {
            __syncthreads();
#pragma unroll
            for (int l = 0; l < 4; ++l) {
                int idx = tid + (l << 8);
                int arow = idx >> 3, ac = idx & 7;
                *(bf16x8*)&As[arow * 72 + ac * 8] =
                    *(const bf16x8*)(h + (size_t)(m0 + arow) * DIM + k0 + ac * 8);
            }
#pragma unroll
            for (int l = 0; l < 2; ++l) {
                int idx = tid + (l << 8);
                int brow = idx >> 3, bc = idx & 7;
                *(bf16x8*)&Bs[brow * 72 + bc * 8] =
                    *(const bf16x8*)(wq2 + (size_t)(n0 + brow) * DIM + k0 + bc * 8);
            }
            __syncthreads();
#pragma unroll
            for (int s = 0; s < 2; ++s) {
                bf16x8 b0 = *(const bf16x8*)&Bs[(wc * 32 + lrow) * 72 + s * 32 + lgrp * 8];
                bf16x8 b1 = *(const bf16x8*)&Bs[(wc * 32 + 16 + lrow) * 72 + s * 32 + lgrp * 8];
#pragma unroll
                for (int m = 0; m < 4; ++m) {
                    bf16x8 a = *(const bf16x8*)&As[(wr * 64 + m * 16 + lrow) * 72 + s * 32 + lgrp * 8];
                    acc[m][0] = __builtin_amdgcn_mfma_f32_16x16x32_bf16(a, b0, acc[m][0], 0, 0, 0);
                    acc[m][1] = __builtin_amdgcn_mfma_f32_16x16x32_bf16(a, b1, acc[m][1], 0, 0, 0);
                }
            }
        }
#pragma unroll
        for (int n = 0; n < 2; ++n) {
            int col = n0 + wc * 32 + n * 16 + lrow;
#pragma unroll
            for (int m = 0; m < 4; ++m)
#pragma unroll
                for (int r = 0; r < 4; ++r) {
                    int row = m0 + wr * 64 + m * 16 + lgrp * 4 + r;
                    qb[(size_t)row * DIM + col] = f2bs(acc[m][n][r] * qscale);
                }
        }
    } else {
        int i = bid - 320;
        int z = i / 15, r_ = i % 15;
        const short* Wt = z ? wv2 : wk2;
        const int Mc = BATCH * NCTX;
        const int m0 = (r_ / 5) * 64, n0 = (r_ % 5) * 64;
        f32x4 acc[4] = {};
        for (int kb = 0; kb < CTXD / 64; ++kb) {
            const int k0 = kb << 6;
            __syncthreads();
#pragma unroll
            for (int l = 0; l < 2; ++l) {
                int idx = tid + (l << 8);
                int arow = idx >> 3, ac = idx & 7;
                int grow = m0 + arow;
                bf16x8 v = {};
                if (grow < Mc) {
                    const float* Af = ctx + (size_t)grow * CTXD + k0 + ac * 8;
#pragma unroll
                    for (int j = 0; j < 8; ++j) v[j] = f2bs(Af[j]);
                }
                *(bf16x8*)&As[arow * 72 + ac * 8] = v;
                *(bf16x8*)&Bs[arow * 72 + ac * 8] =
                    *(const bf16x8*)(Wt + (size_t)(n0 + arow) * CTXD + k0 + ac * 8);
            }
            __syncthreads();
#pragma unroll
            for (int s = 0; s < 2; ++s) {
                bf16x8 a = *(const bf16x8*)&As[(w * 16 + lrow) * 72 + s * 32 + lgrp * 8];
#pragma unroll
                for (int ct = 0; ct < 4; ++ct) {
                    bf16x8 b = *(const bf16x8*)&Bs[(ct * 16 + lrow) * 72 + s * 32 + lgrp * 8];
                    acc[ct] = __builtin_amdgcn_mfma_f32_16x16x32_bf16(a, b, acc[ct], 0, 0, 0);
                }
            }
        }
#pragma unroll
        for (int ct = 0; ct < 4; ++ct) {
            int col = n0 + ct * 16 + lrow;
            int hh = col / DHEAD, d = col - hh * DHEAD;
#pragma unroll
            for (int r = 0; r < 4; ++r) {
                int row = m0 + w * 16 + lgrp * 4 + r;
                if (row >= Mc) continue;
                float v = acc[ct][r];
                if (z == 0) k2[(size_t)row * DIM + col] = f2bs(v);
                else {
                    int b_ = row / NCTX, kv = row - b_ * NCTX;
                    vt2[(size_t)((b_ * HEADS + hh) * 48 + d) * 128 + kv] = f2bs(v);
                }
            }
        }
    }
}

// ---------------- GEGLU on the 128x64 core: dual B tiles (u + gate) --------------------
__global__ void __launch_bounds__(256) geglu128(const short* __restrict__ A,
                           const short* __restrict__ Wt1,
                           const float* __restrict__ b1, short* __restrict__ G)
{
    __shared__ short As[128 * 72];
    __shared__ short Bu[64 * 72];
    __shared__ short Bg[64 * 72];
    const int tid = threadIdx.x;
    const int w = tid >> 6, lane = tid & 63, lrow = lane & 15, lgrp = lane >> 4;
    const int wr = w >> 1, wc = w & 1;
    const int m0 = blockIdx.y * 128, n0 = blockIdx.x * 64;
    f32x4 au[4][2] = {}, ag[4][2] = {};
    for (int k0 = 0; k0 < DIM; k0 += 64) {
        __syncthreads();
#pragma unroll
        for (int l = 0; l < 4; ++l) {
            int idx = tid + (l << 8);
            int arow = idx >> 3, ac = idx & 7;
            *(bf16x8*)&As[arow * 72 + ac * 8] =
                *(const bf16x8*)(A + (size_t)(m0 + arow) * DIM + k0 + ac * 8);
        }
#pragma unroll
        for (int l = 0; l < 2; ++l) {
            int idx = tid + (l << 8);
            int brow = idx >> 3, bc = idx & 7;
            *(bf16x8*)&Bu[brow * 72 + bc * 8] =
                *(const bf16x8*)(Wt1 + (size_t)(n0 + brow) * DIM + k0 + bc * 8);
            *(bf16x8*)&Bg[brow * 72 + bc * 8] =
                *(const bf16x8*)(Wt1 + (size_t)(FFI + n0 + brow) * DIM + k0 + bc * 8);
        }
        __syncthreads();
#pragma unroll
        for (int s = 0; s < 2; ++s) {
            bf16x8 bu0 = *(const bf16x8*)&Bu[(wc * 32 + lrow) * 72 + s * 32 + lgrp * 8];
            bf16x8 bu1 = *(const bf16x8*)&Bu[(wc * 32 + 16 + lrow) * 72 + s * 32 + lgrp * 8];
            bf16x8 bg0 = *(const bf16x8*)&Bg[(wc * 32 + lrow) * 72 + s * 32 + lgrp * 8];
            bf16x8 bg1 = *(const bf16x8*)&Bg[(wc * 32 + 16 + lrow) * 72 + s * 32 + lgrp * 8];
#pragma unroll
            for (int m = 0; m < 4; ++m) {
                bf16x8 a = *(const bf16x8*)&As[(wr * 64 + m * 16 + lrow) * 72 + s * 32 + lgrp * 8];
                au[m][0] = __builtin_amdgcn_mfma_f32_16x16x32_bf16(a, bu0, au[m][0], 0, 0, 0);
                au[m][1] = __builtin_amdgcn_mfma_f32_16x16x32_bf16(a, bu1, au[m][1], 0, 0, 0);
                ag[m][0] = __builtin_amdgcn_mfma_f32_16x16x32_bf16(a, bg0, ag[m][0], 0, 0, 0);
                ag[m][1] = __builtin_amdgcn_mfma_f32_16x16x32_bf16(a, bg1, ag[m][1], 0, 0, 0);
            }
        }
    }
#pragma unroll
    for (int n = 0; n < 2; ++n) {
        int col = n0 + wc * 32 + n * 16 + lrow;
        float bu = b1[col], bg = b1[FFI + col];
#pragma unroll
        for (int m = 0; m < 4; ++m) {
#pragma unroll
            for (int r = 0; r < 4; ++r) {
                int row = m0 + wr * 64 + m * 16 + lgrp * 4 + r;
                float u = au[m][n][r] + bu;
                float g = ag[m][n][r] + bg;
                float gelu = 0.5f * g * (1.f + erff(g * 0.70710678f));
                G[(size_t)row * FFI + col] = f2bs(u * gelu);
            }
        }
    }
}

// ---------------- Flash attention: dual-q waves, deferred PV, SINGLE P buffer ----------
// 4 waves, 128-query tile, KV tiles of 64. body(t): barrier -> commit(t+1) -> issue(t+2)
// -> PV(t-1) -> QK(t) -> exp(t)->P. Single Ps is safe: region is wave-exclusive and LDS
// ops are in-order per wave. LDS 50 KB. K dbuf, V tbuf. p = exp2(s); l via ones-row d=40.
template<bool FULL>
__global__ void __launch_bounds__(256) flash_mfma(const short* __restrict__ Q,
                           const short* __restrict__ Kb,
                           const short* __restrict__ VtG,
                           short* __restrict__ O,
                           int kvlen, int kvs)
{
    __shared__ short Ks[2][64 * 64];
    __shared__ short Vt[3][48 * 64];
    __shared__ short Ps[128 * 64];
    const int tid = threadIdx.x;
    const int w = tid >> 6, lane = tid & 63, lrow = lane & 15, lgrp = lane >> 4;
    const int hh = blockIdx.y, b = blockIdx.z;
    const int q0 = blockIdx.x * 128;
    const int swz = (lrow & 7) << 4;

    for (int i = tid; i < 1024; i += 256) ((bf16x8*)Ks)[i] = (bf16x8){};
    for (int i = tid; i < 1152; i += 256) {
        short fill = (((i % 384) >> 3) == 40) ? (short)0x3F80 : (short)0;  // ones row d=40
        bf16x8 f8 = {fill, fill, fill, fill, fill, fill, fill, fill};
        ((bf16x8*)Vt)[i] = f8;
    }

    const size_t qra = (size_t)(b * NQ + q0 + w * 32 + lrow) * DIM + hh * DHEAD;
    const size_t qrb = qra + (size_t)16 * DIM;
    bf16x8 bq0a = *(const bf16x8*)(Q + qra + lgrp * 8);
    bf16x8 bq0b = *(const bf16x8*)(Q + qrb + lgrp * 8);
    bf16x8 bq1a = {}, bq1b = {};
    if (lgrp == 0) {
        bq1a = *(const bf16x8*)(Q + qra + 32);
        bq1b = *(const bf16x8*)(Q + qrb + 32);
    }

    const int kv0 = tid / 5, cc0 = tid % 5;
    const bool isK1 = tid < 64;
    const int kv1 = (256 + tid) / 5, cc1 = (256 + tid) % 5;
    const int vd1 = (tid - 64) >> 3, vcc1 = (tid - 64) & 7;
    const bool hasV2 = tid < 128;
    const int vd2 = (192 + tid) >> 3, vcc2 = (192 + tid) & 7;

    const size_t kbase = (size_t)b * kvlen;
    const size_t vbase = (size_t)((b * HEADS + hh) * 48);

    const short* kp0 = Kb + (kbase + kv0) * DIM + hh * DHEAD + cc0 * 8;
    const short* kp1 = Kb + (kbase + (isK1 ? kv1 : 0)) * DIM + hh * DHEAD + (isK1 ? cc1 : 0) * 8;
    const short* vp1 = VtG + (vbase + (isK1 ? 0 : vd1)) * kvs + (isK1 ? 0 : vcc1) * 8;
    const short* vp2 = VtG + (vbase + (hasV2 ? vd2 : 0)) * kvs + (hasV2 ? vcc2 : 0) * 8;

    const int koff0 = kv0 * 128 + ((cc0 * 16) ^ ((kv0 & 7) << 4));
    const int koff1 = kv1 * 128 + ((cc1 * 16) ^ ((kv1 & 7) << 4));
    const int voff1 = vd1 * 128 + ((vcc1 * 16) ^ ((vd1 & 7) << 4));
    const int voff2 = vd2 * 128 + ((vcc2 * 16) ^ ((vd2 & 7) << 4));

    bf16x8 st0, st1, st2;
    auto issue = [&]() {
        st0 = *(const bf16x8*)kp0; kp0 += 64 * DIM;
        if (isK1) { st1 = *(const bf16x8*)kp1; kp1 += 64 * DIM; }
        else      { st1 = *(const bf16x8*)vp1; vp1 += 64; }
        if (hasV2) { st2 = *(const bf16x8*)vp2; vp2 += 64; }
    };
    auto commit = [&](char* kb_, char* vb_) {
        *(bf16x8*)(kb_ + koff0) = st0;
        if (isK1)  *(bf16x8*)(kb_ + koff1) = st1;
        else       *(bf16x8*)(vb_ + voff1) = st1;
        if (hasV2) *(bf16x8*)(vb_ + voff2) = st2;
    };

    f32x4 oa[3] = {}, ob[3] = {};

    char* kcur = (char*)Ks[0];
    char* knxt = (char*)Ks[1];
    char* vprev = (char*)Vt[2];
    char* vcur  = (char*)Vt[0];
    char* vnxt  = (char*)Vt[1];
    char* pp = (char*)Ps + (w * 32 + lrow) * 128;

    auto pv_step = [&](char* vb_) {
        __builtin_amdgcn_s_setprio(1);
#pragma unroll
        for (int s = 0; s < 2; ++s) {
            bf16x8 bpa = *(const bf16x8*)(pp + ((s * 64 + lgrp * 16) ^ swz));
            bf16x8 bpb = *(const bf16x8*)(pp + 2048 + ((s * 64 + lgrp * 16) ^ swz));
#pragma unroll
            for (int dt = 0; dt < 3; ++dt) {
                bf16x8 av = *(const bf16x8*)(vb_ + (dt * 16 + lrow) * 128 + ((s * 64 + lgrp * 16) ^ swz));
                oa[dt] = __builtin_amdgcn_mfma_f32_16x16x32_bf16(av, bpa, oa[dt], 0, 0, 0);
                ob[dt] = __builtin_amdgcn_mfma_f32_16x16x32_bf16(av, bpb, ob[dt], 0, 0, 0);
            }
        }
        __builtin_amdgcn_s_setprio(0);
    };

    issue();
    __syncthreads();
    commit(kcur, vcur);
    issue();

    const int ntiles = (kvlen + 63) >> 6;
    for (int t = 0; t < ntiles; ++t) {
        __syncthreads();
        commit(knxt, vnxt);
        issue();

        if (t > 0) pv_step(vprev);

        f32x4 sa[4] = {}, sb[4] = {};
        __builtin_amdgcn_s_setprio(1);
#pragma unroll
        for (int ct = 0; ct < 4; ++ct) {
            const char* krow = kcur + (ct * 16 + lrow) * 128;
            bf16x8 ak0 = *(const bf16x8*)(krow + ((lgrp * 16) ^ swz));
            bf16x8 ak1 = *(const bf16x8*)(krow + ((64 + lgrp * 16) ^ swz));
            sa[ct] = __builtin_amdgcn_mfma_f32_16x16x32_bf16(ak0, bq0a, sa[ct], 0, 0, 0);
            sb[ct] = __builtin_amdgcn_mfma_f32_16x16x32_bf16(ak0, bq0b, sb[ct], 0, 0, 0);
            sa[ct] = __builtin_amdgcn_mfma_f32_16x16x32_bf16(ak1, bq1a, sa[ct], 0, 0, 0);
            sb[ct] = __builtin_amdgcn_mfma_f32_16x16x32_bf16(ak1, bq1b, sb[ct], 0, 0, 0);
        }
        __builtin_amdgcn_s_setprio(0);
        if (!FULL && (t << 6) + 64 > kvlen) {
#pragma unroll
            for (int ct = 0; ct < 4; ++ct)
#pragma unroll
                for (int r = 0; r < 4; ++r)
                    if ((t << 6) + ct * 16 + lgrp * 4 + r >= kvlen) { sa[ct][r] = -1e30f; sb[ct][r] = -1e30f; }
        }
#pragma unroll
        for (int ct = 0; ct < 4; ++ct) {
            float a0 = __builtin_amdgcn_exp2f(sa[ct][0]);
            float a1 = __builtin_amdgcn_exp2f(sa[ct][1]);
            float a2 = __builtin_amdgcn_exp2f(sa[ct][2]);
            float a3 = __builtin_amdgcn_exp2f(sa[ct][3]);
            u32x2 pka; pka[0] = pkbf(a1, a0); pka[1] = pkbf(a3, a2);
            *(u32x2*)(pp + ((ct * 32 + lgrp * 8) ^ swz)) = pka;
            float b0 = __builtin_amdgcn_exp2f(sb[ct][0]);
            float b1 = __builtin_amdgcn_exp2f(sb[ct][1]);
            float b2 = __builtin_amdgcn_exp2f(sb[ct][2]);
            float b3 = __builtin_amdgcn_exp2f(sb[ct][3]);
            u32x2 pkb; pkb[0] = pkbf(b1, b0); pkb[1] = pkbf(b3, b2);
            *(u32x2*)(pp + 2048 + ((ct * 32 + lgrp * 8) ^ swz)) = pkb;
        }
        { char* tk = kcur; kcur = knxt; knxt = tk; }
        { char* tv = vprev; vprev = vcur; vcur = vnxt; vnxt = tv; }
    }
    pv_step(vprev);

    float la = __shfl(oa[2][0], 32 + lrow);
    float lb = __shfl(ob[2][0], 32 + lrow);
    float ia = 1.f / la, ib = 1.f / lb;
#pragma unroll
    for (int dt = 0; dt < 3; ++dt) {
        int dbase = dt * 16 + lgrp * 4;
        if (dbase < DHEAD) {
            u32x2 ova, ovb;
            ova[0] = pkbf(oa[dt][1] * ia, oa[dt][0] * ia);
            ova[1] = pkbf(oa[dt][3] * ia, oa[dt][2] * ia);
            *(u32x2*)(O + qra + dbase) = ova;
            ovb[0] = pkbf(ob[dt][1] * ib, ob[dt][0] * ib);
            ovb[1] = pkbf(ob[dt][3] * ib, ob[dt][2] * ib);
            *(u32x2*)(O + qrb + dbase) = ovb;
        }
    }
}

extern "C" void kernel_launch(void* const* d_in, const int* in_sizes, int n_in,
                              void* d_out, int out_size, void* d_ws, size_t ws_size,
                              hipStream_t stream)
{
    const float* x      = (const float*)d_in[0];
    const float* ctx    = (const float*)d_in[1];
    const float* ln1_w  = (const float*)d_in[2];
    const float* ln1_b  = (const float*)d_in[3];
    const float* ln2_w  = (const float*)d_in[4];
    const float* ln2_b  = (const float*)d_in[5];
    const float* ln3_w  = (const float*)d_in[6];
    const float* ln3_b  = (const float*)d_in[7];
    const float* a1_Wq  = (const float*)d_in[8];
    const float* a1_Wk  = (const float*)d_in[9];
    const float* a1_Wv  = (const float*)d_in[10];
    const float* a1_Wo  = (const float*)d_in[11];
    const float* a1_bo  = (const float*)d_in[12];
    const float* a2_Wq  = (const float*)d_in[13];
    const float* a2_Wk  = (const float*)d_in[14];
    const float* a2_Wv  = (const float*)d_in[15];
    const float* a2_Wo  = (const float*)d_in[16];
    const float* a2_bo  = (const float*)d_in[17];
    const float* ff_W1  = (const float*)d_in[18];
    const float* ff_b1  = (const float*)d_in[19];
    const float* ff_W2  = (const float*)d_in[20];
    const float* ff_b2  = (const float*)d_in[21];

    const int M = BATCH * NQ;  // 8192
    const float qscale2 = (float)(0.15811388300841898 * 1.4426950408889634);

    char* p = (char*)d_ws;
    auto carve = [&](size_t bytes) { char* r = p; p += (bytes + 255) & ~255ULL; return r; };
    short* h       = (short*)carve((size_t)M * DIM * 2);
    short* qb      = (short*)carve((size_t)M * DIM * 2);
    short* kbuf    = (short*)carve((size_t)M * DIM * 2);
    short* attnout = (short*)carve((size_t)M * DIM * 2);
    short* resb    = (short*)carve((size_t)M * DIM * 2);
    short* gbuf    = (short*)carve((size_t)M * FFI * 2);
    short* VtS     = (short*)carve((size_t)BATCH * HEADS * 48 * NQ * 2);
    short* Vt2     = (short*)carve((size_t)BATCH * HEADS * 48 * 128 * 2);
    short* k2      = (short*)carve((size_t)512 * DIM * 2);
    short* wtq1    = (short*)carve((size_t)DIM * DIM * 2);
    short* wtk1    = (short*)carve((size_t)DIM * DIM * 2);
    short* wtv1    = (short*)carve((size_t)DIM * DIM * 2);
    short* wto1    = (short*)carve((size_t)DIM * DIM * 2);
    short* wtq2    = (short*)carve((size_t)DIM * DIM * 2);
    short* wto2    = (short*)carve((size_t)DIM * DIM * 2);
    short* wtk2    = (short*)carve((size_t)DIM * CTXD * 2);
    short* wtv2    = (short*)carve((size_t)DIM * CTXD * 2);
    short* wt1     = (short*)carve((size_t)2 * FFI * DIM * 2);
    short* wt2     = (short*)carve((size_t)DIM * FFI * 2);

    dim3 blk(256);
    dim3 g128(DIM / 64, M / 128);         // (5,64)
    dim3 gattn(NQ / 128, HEADS, BATCH);   // (32,8,2)

    // 1. prep: all weight transposes + LN1 (one launch)
    prep_kernel<<<2280 + M / 4, blk, 0, stream>>>(
        a1_Wq, a1_Wk, a1_Wv, a1_Wo, a2_Wq, a2_Wo, a2_Wk, a2_Wv, ff_W1, ff_W2,
        wtq1, wtk1, wtv1, wto1, wtq2, wto2, wtk2, wtv2, wt1, wt2,
        x, ln1_w, ln1_b, h);
    // 2. self QKV
    qkv128<<<dim3(5, 64, 3), blk, 0, stream>>>(h, wtq1, wtk1, wtv1, qb, kbuf, VtS, qscale2);
    // 3. flash self-attn
    flash_mfma<true><<<gattn, blk, 0, stream>>>(qb, kbuf, VtS, attnout, NQ, NQ);
    // 4. out-proj + residual
    gemm128<1><<<g128, blk, 0, stream>>>(attnout, wto1, a1_bo, x, resb, nullptr, nullptr, DIM, DIM, 1.f);
    // 5. LN2
    ln_b16<<<M / 4, blk, 0, stream>>>(resb, ln2_w, ln2_b, h);
    // 6. cross Q + cross K/V merged (one launch)
    crossq_kv<<<350, blk, 0, stream>>>(h, wtq2, ctx, wtk2, wtv2, qb, k2, Vt2, qscale2);
    // 7. flash cross-attn
    flash_mfma<false><<<gattn, blk, 0, stream>>>(qb, k2, Vt2, attnout, NCTX, 128);
    // 8. out-proj accumulate
    gemm128<2><<<g128, blk, 0, stream>>>(attnout, wto2, a2_bo, nullptr, resb, nullptr, nullptr, DIM, DIM, 1.f);
    // 9. LN3
    ln_b16<<<M / 4, blk, 0, stream>>>(resb, ln3_w, ln3_b, h);
    // 10. GEGLU
    geglu128<<<dim3(FFI / 64, M / 128), blk, 0, stream>>>(h, wt1, ff_b1, gbuf);
    // 11. FF out + residual -> d_out (f32)
    gemm128<3><<<g128, blk, 0, stream>>>(gbuf, wt2, ff_b2, nullptr, resb, nullptr, (float*)d_out, DIM, FFI, 1.f);
}